// Round 2
// baseline (227.312 us; speedup 1.0000x reference)
//
#include <hip/hip_runtime.h>
#include <cstdint>
#include <cmath>

#define Bn 4096
#define Dn 256
#define On 256

typedef __bf16 v8bf __attribute__((ext_vector_type(8)));
typedef float  v4f  __attribute__((ext_vector_type(4)));
typedef unsigned short us8 __attribute__((ext_vector_type(8)));

__device__ __forceinline__ unsigned short f2bf(float f) {
    // round-to-nearest-even fp32 -> bf16 (inputs are finite normals)
    unsigned int u = __builtin_bit_cast(unsigned int, f);
    unsigned int r = (u + 0x7fffu + ((u >> 16) & 1u)) >> 16;
    return (unsigned short)r;
}

__device__ __forceinline__ void gl_lds16(const void* g, void* l) {
    __builtin_amdgcn_global_load_lds(
        (const __attribute__((address_space(1))) void*)(uintptr_t)g,
        (__attribute__((address_space(3))) void*)(uintptr_t)l, 16, 0, 0);
}

// ---------------------------------------------------------------------------
// Kernel 1: x -> bf16 only (the A-build lives in fuzzy_main's prologue).
// ---------------------------------------------------------------------------
__global__ __launch_bounds__(256) void prep_x(const float* __restrict__ x,
                                              unsigned short* __restrict__ xb) {
    const int tid = threadIdx.x;
    const int cb  = blockIdx.x;
#pragma unroll
    for (int s = 0; s < 4; ++s) {
        const int i = cb * 4096 + s * 1024 + tid * 4;
        const float4 v = *(const float4*)(x + i);
        ushort4 u;
        u.x = f2bf(v.x); u.y = f2bf(v.y); u.z = f2bf(v.z); u.w = f2bf(v.w);
        *(ushort4*)(xb + i) = u;
    }
}

// ---------------------------------------------------------------------------
// Fragment extraction for one staged 64x64 tile pair (ti,tj), ti<=tj.
// Tile T is LINEAR [64][64] fp32 in LDS: T[r][c] = rots[o][ti*64+r][tj*64+c].
// Produces the exact A' fragment order the proven kernel used:
//   af[mi][t][j] = A[o][i = wv*64+mi*16+frow][kc = t*32+quad*8+j]
// Wave ti takes rows (contiguous float4 reads); wave tj takes columns
// (transposed scalar reads, 4-way bank conflict = 1.58x, negligible here);
// diag uses scales. TIv/TJv compile-time -> all af indices static (no spill).
// ---------------------------------------------------------------------------
template <int TIv, int TJv>
__device__ __forceinline__ void extract_pair(const float* T, v8bf (&af)[4][8],
                                             const float (&sc4)[4],
                                             int wv, int frow, int quad) {
    if (TIv == TJv) {
        if (wv == TIv) {                 // diagonal tile: ternary with scales
#pragma unroll
            for (int mi = 0; mi < 4; ++mi) {
                const int r = mi * 16 + frow;
#pragma unroll
                for (int kl = 0; kl < 2; ++kl) {
                    us8 u;
#pragma unroll
                    for (int q = 0; q < 8; ++q) {
                        const int cc = kl * 32 + quad * 8 + q;
                        const float v = (r < cc) ? T[r * 64 + cc]
                                      : ((r > cc) ? T[cc * 64 + r] : sc4[mi]);
                        u[q] = f2bf(v);
                    }
                    af[mi][TJv * 2 + kl] = __builtin_bit_cast(v8bf, u);
                }
            }
        }
    } else {
        if (wv == TIv) {                 // row side: i-block=TIv, k-block=TJv
#pragma unroll
            for (int mi = 0; mi < 4; ++mi) {
                const int r = mi * 16 + frow;
#pragma unroll
                for (int kl = 0; kl < 2; ++kl) {
                    const float4 a = *(const float4*)&T[r * 64 + kl * 32 + quad * 8];
                    const float4 b = *(const float4*)&T[r * 64 + kl * 32 + quad * 8 + 4];
                    us8 u;
                    u[0] = f2bf(a.x); u[1] = f2bf(a.y); u[2] = f2bf(a.z); u[3] = f2bf(a.w);
                    u[4] = f2bf(b.x); u[5] = f2bf(b.y); u[6] = f2bf(b.z); u[7] = f2bf(b.w);
                    af[mi][TJv * 2 + kl] = __builtin_bit_cast(v8bf, u);
                }
            }
        } else if (wv == TJv) {          // col side: i-block=TJv, k-block=TIv
#pragma unroll
            for (int mi = 0; mi < 4; ++mi) {
                const int c = mi * 16 + frow;
#pragma unroll
                for (int kl = 0; kl < 2; ++kl) {
                    us8 u;
#pragma unroll
                    for (int q = 0; q < 8; ++q)
                        u[q] = f2bf(T[(kl * 32 + quad * 8 + q) * 64 + c]);
                    af[mi][TIv * 2 + kl] = __builtin_bit_cast(v8bf, u);
                }
            }
        }
    }
}

// Inline-asm waits + compile-scheduler fence (guide rule #18: hipcc may move
// ops across inline-asm s_waitcnt despite "memory"; sched_barrier(0) pins it).
#define WAITV(N)                                         \
    do {                                                 \
        asm volatile("s_waitcnt vmcnt(" #N ")" ::: "memory"); \
        __builtin_amdgcn_sched_barrier(0);               \
    } while (0)
#define LGKM0()                                          \
    do {                                                 \
        asm volatile("s_waitcnt lgkmcnt(0)" ::: "memory"); \
        __builtin_amdgcn_sched_barrier(0);               \
    } while (0)
#define BARF()                                           \
    do {                                                 \
        __builtin_amdgcn_sched_barrier(0);               \
        __builtin_amdgcn_s_barrier();                    \
        __builtin_amdgcn_sched_barrier(0);               \
    } while (0)

// Stage rot tile (TIv,TJv) of this block's o into LDS slot SLOT (16 KB,
// linear [64][64] fp32). LDS dest offset = idx*16B -> exactly the
// wave-uniform-base + lane*16 layout global_load_lds requires.
#define STAGE_T(TIv, TJv, SLOT)                                              \
    do {                                                                     \
        const float* s_ = rbase + (TIv) * (64 * Dn) + (TJv) * 64;            \
        float* d_ = tileB + (SLOT) * 4096;                                   \
        _Pragma("unroll")                                                    \
        for (int s = 0; s < 4; ++s) {                                        \
            const int idx = s * 256 + tid;                                   \
            gl_lds16(s_ + (idx >> 4) * Dn + (idx & 15) * 4, d_ + idx * 4);   \
        }                                                                    \
    } while (0)

// ---------------------------------------------------------------------------
// Kernel 2: fused A-build + GEMM + norm + bell. Main K-loop identical to the
// proven 215us kernel; the A' HBM round-trip (33.5 MB write + read) and the
// ~85us prep kernel are replaced by a ~15us in-kernel prologue: 10 tile-pairs
// of rots[o] staged through 3 rotating 16 KB LDS slots (counted vmcnt(8)
// keeps 2 stages in flight across barriers; the needed stage is always >=8
// vm-instrs older than the wait, so compiler-inserted loads can only
// over-synchronize), fragments extracted straight into the af registers.
// Numerics bit-identical to the proven version.
// ---------------------------------------------------------------------------
__global__ __launch_bounds__(256, 2) void fuzzy_main(
    const float* __restrict__ rots, const float* __restrict__ scales,
    const unsigned short* __restrict__ xb, const float* __restrict__ cent,
    const float* __restrict__ bvals, float* __restrict__ out) {
    __shared__ __align__(16) unsigned short Xs[2][4][64 * 64];  // 64 KB dbuf
    __shared__ float ssbuf[2][4][64];                           // parity dbuf

    const int tid  = threadIdx.x;
    const int lane = tid & 63;
    const int wv   = tid >> 6;
    // grid 512 = 8 xcd x 32 olow x 2 bhalf
    const int Lb = blockIdx.x;
    const int o     = (Lb & 7) * 32 + ((Lb >> 3) & 31);
    const int bhalf = Lb >> 8;

    const int frow = lane & 15, quad = lane >> 4, f3 = lane & 7;
    const int lr = lane >> 3, ls = lane & 7;
    const int ksw = (ls ^ lr) * 8;       // swizzled source k-offset within chunk

    float cv[4][4];
#pragma unroll
    for (int mi = 0; mi < 4; ++mi)       // centroid values for this wave's i's
#pragma unroll
        for (int rg = 0; rg < 4; ++rg)
            cv[mi][rg] = cent[o * Dn + wv * 64 + mi * 16 + quad * 4 + rg];

    float sc4[4];                        // scales for diag extraction
#pragma unroll
    for (int mi = 0; mi < 4; ++mi)
        sc4[mi] = scales[o * Dn + wv * 64 + mi * 16 + frow];

    // ---- A-build prologue ----
    float* const tileB = (float*)&Xs[0][0][0];          // 3 slots x 4096 fp32
    const float* const rbase = rots + ((size_t)o << 16);

    v8bf af[4][8];                       // [mi][t]  128 VGPRs

    STAGE_T(0, 0, 0); STAGE_T(0, 1, 1); STAGE_T(0, 2, 2);

    // pair p: wait stage p (2 newer stages = 8 vm-instrs stay in flight),
    // barrier, extract, drain own LDS reads, barrier, issue stage p+3.
    WAITV(8); BARF(); extract_pair<0, 0>(tileB + 0,    af, sc4, wv, frow, quad); LGKM0(); BARF(); STAGE_T(0, 3, 0);
    WAITV(8); BARF(); extract_pair<0, 1>(tileB + 4096, af, sc4, wv, frow, quad); LGKM0(); BARF(); STAGE_T(1, 1, 1);
    WAITV(8); BARF(); extract_pair<0, 2>(tileB + 8192, af, sc4, wv, frow, quad); LGKM0(); BARF(); STAGE_T(1, 2, 2);
    WAITV(8); BARF(); extract_pair<0, 3>(tileB + 0,    af, sc4, wv, frow, quad); LGKM0(); BARF(); STAGE_T(1, 3, 0);
    WAITV(8); BARF(); extract_pair<1, 1>(tileB + 4096, af, sc4, wv, frow, quad); LGKM0(); BARF(); STAGE_T(2, 2, 1);
    WAITV(8); BARF(); extract_pair<1, 2>(tileB + 8192, af, sc4, wv, frow, quad); LGKM0(); BARF(); STAGE_T(2, 3, 2);
    WAITV(8); BARF(); extract_pair<1, 3>(tileB + 0,    af, sc4, wv, frow, quad); LGKM0(); BARF(); STAGE_T(3, 3, 0);
    WAITV(8); BARF(); extract_pair<2, 2>(tileB + 4096, af, sc4, wv, frow, quad); LGKM0(); BARF();
    WAITV(4); BARF(); extract_pair<2, 3>(tileB + 8192, af, sc4, wv, frow, quad); LGKM0(); BARF();
    WAITV(0); BARF(); extract_pair<3, 3>(tileB + 0,    af, sc4, wv, frow, quad); LGKM0(); BARF();

    // ---- stage btile 0 into buffer 0 (unchanged main pipeline) ----
    {
        const int b0 = bhalf * 2048;
#pragma unroll
        for (int c = 0; c < 4; ++c)
#pragma unroll
            for (int q = 0; q < 2; ++q) {
                const int row = (wv * 2 + q) * 8 + lr;
                gl_lds16(xb + (size_t)(b0 + row) * Dn + c * 64 + ksw,
                         &Xs[0][c][row * 64 + ls * 8]);
            }
    }
    __syncthreads();

    for (int it = 0; it < 32; ++it) {
        const int buf = it & 1;
        const int b0  = bhalf * 2048 + it * 64;
        if (it < 31) {                   // prefetch next btile into other buffer
            const int nb0 = b0 + 64;
#pragma unroll
            for (int c = 0; c < 4; ++c)
#pragma unroll
                for (int q = 0; q < 2; ++q) {
                    const int row = (wv * 2 + q) * 8 + lr;
                    gl_lds16(xb + (size_t)(nb0 + row) * Dn + c * 64 + ksw,
                             &Xs[buf ^ 1][c][row * 64 + ls * 8]);
                }
        }

        v4f acc[4][4];
#pragma unroll
        for (int mi = 0; mi < 4; ++mi)
#pragma unroll
            for (int ni = 0; ni < 4; ++ni)
                acc[mi][ni] = v4f{0.f, 0.f, 0.f, 0.f};

#pragma unroll
        for (int t = 0; t < 8; ++t) {
            v8bf xf[4];
            const int sl = ((t & 1) * 4 + quad) ^ f3;   // proven 0-conflict class
#pragma unroll
            for (int ni = 0; ni < 4; ++ni)
                xf[ni] = *(const v8bf*)&Xs[buf][t >> 1][(ni * 16 + frow) * 64 + sl * 8];
#pragma unroll
            for (int mi = 0; mi < 4; ++mi)
#pragma unroll
                for (int ni = 0; ni < 4; ++ni)
                    acc[mi][ni] = __builtin_amdgcn_mfma_f32_16x16x32_bf16(
                        af[mi][t], xf[ni], acc[mi][ni], 0, 0, 0);
        }

        // epilogue: partial sum_i y^2 for this wave's 64 i (C/D map verified:
        // col=lane&15=b, row=quad*4+rg=i); parity-buffered ssbuf.
#pragma unroll
        for (int ni = 0; ni < 4; ++ni) {
            float v = 0.f;
#pragma unroll
            for (int mi = 0; mi < 4; ++mi)
#pragma unroll
                for (int rg = 0; rg < 4; ++rg) {
                    const float y = acc[mi][ni][rg] + cv[mi][rg];
                    v += y * y;
                }
            v += __shfl_xor(v, 16);
            v += __shfl_xor(v, 32);
            if (lane < 16) ssbuf[buf][wv][ni * 16 + lane] = v;
        }
        __syncthreads();   // staging of buf^1 done (covered by MFMA burst),
                           // ssbuf[buf] visible; next iter writes ssbuf[buf^1]
        if (tid < 64) {
            const float ssq = ssbuf[buf][0][tid] + ssbuf[buf][1][tid] +
                              ssbuf[buf][2][tid] + ssbuf[buf][3][tid];
            out[(size_t)(b0 + tid) * On + o] = 1.0f / (1.0f + powf(ssq, bvals[o]));
        }
    }
}

// ---------------------------------------------------------------------------
// Fallback (only if d_ws is too small): exact fp32, slow but correct.
// ---------------------------------------------------------------------------
__global__ void fallback_kernel(const float* __restrict__ x, const float* __restrict__ scales,
                                const float* __restrict__ rots, const float* __restrict__ cent,
                                const float* __restrict__ bvals, float* __restrict__ out) {
    const int b = blockIdx.x * blockDim.x + threadIdx.x;
    const int o = blockIdx.y;
    if (b >= Bn) return;
    const float* R  = rots + (size_t)o * Dn * Dn;
    const float* xv = x + (size_t)b * Dn;
    float ss = 0.f;
    for (int i = 0; i < Dn; ++i) {
        float a = cent[o * Dn + i];
        for (int j = 0; j < Dn; ++j) {
            const float w = (j > i) ? R[i * Dn + j]
                          : ((j < i) ? R[j * Dn + i] : scales[o * Dn + i]);
            a += w * xv[j];
        }
        ss += a * a;
    }
    out[(size_t)b * On + o] = 1.f / (1.f + powf(ss, bvals[o]));
}

extern "C" void kernel_launch(void* const* d_in, const int* in_sizes, int n_in,
                              void* d_out, int out_size, void* d_ws, size_t ws_size,
                              hipStream_t stream) {
    const float* x         = (const float*)d_in[0];
    const float* scales    = (const float*)d_in[1];
    const float* rots      = (const float*)d_in[2];
    const float* centroids = (const float*)d_in[3];
    const float* bvals     = (const float*)d_in[4];
    float* out = (float*)d_out;

    const size_t needX = (size_t)Bn * Dn * sizeof(unsigned short);      // 2.1 MB

    if (ws_size >= needX) {
        unsigned short* xb = (unsigned short*)d_ws;
        prep_x<<<dim3(256), 256, 0, stream>>>(x, xb);
        fuzzy_main<<<dim3(512), 256, 0, stream>>>(rots, scales, xb, centroids, bvals, out);
    } else {
        fallback_kernel<<<dim3(Bn / 256, On), 256, 0, stream>>>(x, scales, rots, centroids,
                                                                bvals, out);
    }
}

// Round 4
// 225.893 us; speedup vs baseline: 1.0063x; 1.0063x over previous
//
#include <hip/hip_runtime.h>
#include <cstdint>
#include <cmath>

#define Bn 4096
#define Dn 256
#define On 256

typedef __bf16 v8bf __attribute__((ext_vector_type(8)));
typedef float  v16f __attribute__((ext_vector_type(16)));
typedef unsigned short us8 __attribute__((ext_vector_type(8)));

__device__ __forceinline__ unsigned short f2bf(float f) {
    // round-to-nearest-even fp32 -> bf16 (inputs are finite normals)
    unsigned int u = __builtin_bit_cast(unsigned int, f);
    unsigned int r = (u + 0x7fffu + ((u >> 16) & 1u)) >> 16;
    return (unsigned short)r;
}

__device__ __forceinline__ void gl_lds16(const void* g, void* l) {
    __builtin_amdgcn_global_load_lds(
        (const __attribute__((address_space(1))) void*)(uintptr_t)g,
        (__attribute__((address_space(3))) void*)(uintptr_t)l, 16, 0, 0);
}

// ---------------------------------------------------------------------------
// Kernel 1: x (fp32, [b][k] row-major) -> xbT (bf16, k-major 16B units:
// unit g = kc*Bn + b holds x[b][kc*8 .. kc*8+8]).  LDS-transpose per block:
// 64 b x 64 k tile, coalesced loads AND coalesced stores.
// ---------------------------------------------------------------------------
__global__ __launch_bounds__(256) void prep_x(const float* __restrict__ x,
                                              unsigned short* __restrict__ xbT) {
    __shared__ float t[64][68];          // +4 pad: conflict-free col reads
    const int tid = threadIdx.x;
    const int bb = blockIdx.x >> 2;      // 64 b-tiles of 64
    const int kb = blockIdx.x & 3;       // 4 k-quarters of 64
    const int b0 = bb * 64;
#pragma unroll
    for (int s = 0; s < 4; ++s) {
        const int idx = s * 256 + tid;
        const int r = idx >> 4, c4 = idx & 15;
        const float4 v = *(const float4*)(x + (size_t)(b0 + r) * Dn + kb * 64 + c4 * 4);
        *(float4*)&t[r][c4 * 4] = v;
    }
    __syncthreads();
    const int lane = tid & 63, wv = tid >> 6;
#pragma unroll
    for (int s = 0; s < 2; ++s) {
        const int kcl = s * 4 + wv;      // 0..7 local k-chunk
        us8 u;
#pragma unroll
        for (int q = 0; q < 8; ++q) u[q] = f2bf(t[lane][kcl * 8 + q]);
        // unit g = (kb*8+kcl)*Bn + b0 + lane -> consecutive lanes contiguous
        *(us8*)(xbT + ((size_t)(kb * 8 + kcl) * Bn + b0 + lane) * 8) = u;
    }
}

// ---------------------------------------------------------------------------
// Fragment extraction for one staged 64x64 tile pair (ti,tj), ti<=tj.
// Tile slot T is [64][64] fp32 with ROW-SWIZZLE: element (r,c) lives at
// T[r*64 + (c ^ ((r&7)<<2))] (pre-swizzled at the global source, so both
// float4 row reads and per-lane column reads are LDS-bank-conflict-free).
// Produces af[mt][ks] for the 32x32x16 A-operand layout:
//   af[mt][ks][j] = A[o][i = wv*64 + mt*32 + (lane&31)]
//                      [k = ks*16 + (lane>>5)*8 + j]
// Row side (wv==ti): contiguous float4 reads. Col side (wv==tj): scalar
// reads, banks distinct per half-wave. Diag uses scales on r==c.
// ---------------------------------------------------------------------------
template <int TI, int TJ>
__device__ __forceinline__ void extract_pair(const float* T, v8bf (&af)[2][16],
                                             const float (&sc2)[2],
                                             int wv, int lane) {
    const int l31 = lane & 31, hw = lane >> 5;
    if (TI == TJ) {
        if (wv == TI) {                  // diagonal tile
#pragma unroll
            for (int mt = 0; mt < 2; ++mt) {
                const int r = mt * 32 + l31;
                const int mr = (r & 7) << 2;
#pragma unroll
                for (int kq = 0; kq < 4; ++kq) {
                    us8 u;
#pragma unroll
                    for (int q = 0; q < 8; ++q) {
                        const int c = kq * 16 + hw * 8 + q;
                        const float v = (r < c) ? T[r * 64 + (c ^ mr)]
                                      : ((r > c) ? T[c * 64 + (r ^ ((c & 7) << 2))]
                                                 : sc2[mt]);
                        u[q] = f2bf(v);
                    }
                    af[mt][TJ * 4 + kq] = __builtin_bit_cast(v8bf, u);
                }
            }
        }
    } else {
        if (wv == TI) {                  // row side: i-block=TI, k-block=TJ
#pragma unroll
            for (int mt = 0; mt < 2; ++mt) {
                const int r = mt * 32 + l31;
                const int mr = (r & 7) << 2;
#pragma unroll
                for (int kq = 0; kq < 4; ++kq) {
                    const int c0 = kq * 16 + hw * 8;
                    const float4 a = *(const float4*)&T[r * 64 + (c0 ^ mr)];
                    const float4 b = *(const float4*)&T[r * 64 + ((c0 + 4) ^ mr)];
                    us8 u;
                    u[0] = f2bf(a.x); u[1] = f2bf(a.y); u[2] = f2bf(a.z); u[3] = f2bf(a.w);
                    u[4] = f2bf(b.x); u[5] = f2bf(b.y); u[6] = f2bf(b.z); u[7] = f2bf(b.w);
                    af[mt][TJ * 4 + kq] = __builtin_bit_cast(v8bf, u);
                }
            }
        } else if (wv == TJ) {           // col side: i-block=TJ, k-block=TI
#pragma unroll
            for (int mt = 0; mt < 2; ++mt) {
                const int cL = mt * 32 + l31;
#pragma unroll
                for (int kq = 0; kq < 4; ++kq) {
                    us8 u;
#pragma unroll
                    for (int q = 0; q < 8; ++q) {
                        const int rL = kq * 16 + hw * 8 + q;
                        u[q] = f2bf(T[rL * 64 + (cL ^ ((rL & 7) << 2))]);
                    }
                    af[mt][TI * 4 + kq] = __builtin_bit_cast(v8bf, u);
                }
            }
        }
    }
}

// Inline-asm waits + compile-scheduler fence (rule #18).
#define WAITV(N)                                              \
    do {                                                      \
        asm volatile("s_waitcnt vmcnt(" #N ")" ::: "memory"); \
        __builtin_amdgcn_sched_barrier(0);                    \
    } while (0)
#define LGKM0()                                               \
    do {                                                      \
        asm volatile("s_waitcnt lgkmcnt(0)" ::: "memory");    \
        __builtin_amdgcn_sched_barrier(0);                    \
    } while (0)
#define BARF()                                                \
    do {                                                      \
        __builtin_amdgcn_sched_barrier(0);                    \
        __builtin_amdgcn_s_barrier();                         \
        __builtin_amdgcn_sched_barrier(0);                    \
    } while (0)

// Stage rot tile (TIv,TJv) into slot DST (16 KB) with source pre-swizzle:
// LDS unit u = r*16 + c4' receives global floats c = (c4'^(r&7))*4 .. +4,
// i.e. LDS[(r, c)] = global (r, c ^ ((r&7)<<2)).  Dest is linear (the
// wave-uniform-base + lane*16 layout global_load_lds requires).
#define STAGE_T(TIv, TJv, DST)                                               \
    do {                                                                     \
        const float* s_ = rbase + (TIv) * (64 * Dn) + (TJv) * 64;            \
        _Pragma("unroll")                                                    \
        for (int s = 0; s < 4; ++s) {                                        \
            const int idx = s * 256 + tid;                                   \
            const int r = idx >> 4, c4 = idx & 15;                           \
            gl_lds16(s_ + (size_t)r * Dn + ((c4 ^ (r & 7)) * 4),             \
                     (DST) + idx * 4);                                       \
        }                                                                    \
    } while (0)

// Stage one 64-b X tile (k-major) into Xs[BUF]: unit kc*64 + b, linear dest.
#define XSTAGE(BUF, B0)                                                      \
    do {                                                                     \
        _Pragma("unroll")                                                    \
        for (int s = 0; s < 8; ++s) {                                        \
            gl_lds16(xbT + ((size_t)(s * 4 + wv) * Bn + (B0) + lane) * 8,    \
                     &Xs[BUF][s * 256 + tid][0]);                            \
        }                                                                    \
    } while (0)

// ---------------------------------------------------------------------------
// Kernel 2: fused A-build + GEMM + norm + bell, 32x32x16 MFMA.
// Per block: one o, half the batch. 4 waves x 64-i strips, A resident in
// registers (af[2][16] = 128 VGPR). Prologue: 10 rot tiles staged through 4
// rotating 16 KB slots (2 rounds in flight, counted vmcnt(8)), all 4 waves
// extracting concurrently. Main loop: k-major X LDS (conflict-free b128
// reads, no swizzle), 64 MFMA/iter/wave, single shfl_xor reduction, cent
// added fp32 from LDS, out-write deferred one iter and spread over 4 waves.
// ---------------------------------------------------------------------------
__global__ __launch_bounds__(256, 2) void fuzzy_main(
    const float* __restrict__ rots, const float* __restrict__ scales,
    const unsigned short* __restrict__ xbT, const float* __restrict__ cent,
    const float* __restrict__ bvals, float* __restrict__ out) {
    __shared__ __align__(16) unsigned short Xs[2][2048][8];  // 64 KB dbuf
    __shared__ float ssbuf[2][4][64];                        // parity dbuf
    __shared__ float centL[Dn];

    const int tid  = threadIdx.x;
    const int lane = tid & 63;
    const int wv   = tid >> 6;
    const int l31  = lane & 31, hw = lane >> 5;
    // grid 512 = 8 xcd x 32 olow x 2 bhalf
    const int Lb = blockIdx.x;
    const int o     = (Lb & 7) * 32 + ((Lb >> 3) & 31);
    const int bhalf = Lb >> 8;

    centL[tid] = cent[o * Dn + tid];
    float sc2[2];
#pragma unroll
    for (int mt = 0; mt < 2; ++mt)
        sc2[mt] = scales[o * Dn + wv * 64 + mt * 32 + l31];
    const float bv = bvals[o];

    WAITV(0);   // drain the cent/scales vector loads -> clean vmcnt counting

    // ---- A-build prologue: 4 slots, 2 rounds in flight ----
    float* const S0 = (float*)&Xs[1][0][0];
    float* const S1 = S0 + 4096;
    float* const S2 = (float*)&Xs[0][0][0];
    float* const S3 = S2 + 4096;
    const float* const rbase = rots + ((size_t)o << 16);

    v8bf af[2][16];                      // 128 VGPRs

    STAGE_T(0, 1, S0); STAGE_T(2, 3, S1);        // R1
    STAGE_T(0, 2, S2); STAGE_T(1, 3, S3);        // R2   [16 in flight]
    WAITV(8); BARF();                            // R1 ready
    extract_pair<0, 1>(S0, af, sc2, wv, lane);   // w0 row, w1 col
    extract_pair<2, 3>(S1, af, sc2, wv, lane);   // w2 row, w3 col
    LGKM0(); BARF();
    STAGE_T(0, 3, S0); STAGE_T(1, 2, S1);        // R3   [R2+R3 = 16]
    WAITV(8); BARF();                            // R2 ready
    extract_pair<0, 2>(S2, af, sc2, wv, lane);   // w0 row, w2 col
    extract_pair<1, 3>(S3, af, sc2, wv, lane);   // w1 row, w3 col
    LGKM0(); BARF();
    STAGE_T(0, 0, S2); STAGE_T(1, 1, S3);        // R4   [R3+R4 = 16]
    WAITV(8); BARF();                            // R3 ready
    extract_pair<0, 3>(S0, af, sc2, wv, lane);   // w0 row, w3 col
    extract_pair<1, 2>(S1, af, sc2, wv, lane);   // w1 row, w2 col
    LGKM0(); BARF();
    STAGE_T(2, 2, S0); STAGE_T(3, 3, S1);        // R5   [R4+R5 = 16]
    WAITV(8); BARF();                            // R4 ready
    extract_pair<0, 0>(S2, af, sc2, wv, lane);   // w0 diag
    extract_pair<1, 1>(S3, af, sc2, wv, lane);   // w1 diag
    LGKM0(); BARF();
    WAITV(0); BARF();                            // R5 ready
    extract_pair<2, 2>(S0, af, sc2, wv, lane);   // w2 diag
    extract_pair<3, 3>(S1, af, sc2, wv, lane);   // w3 diag
    LGKM0(); BARF();

    // ---- stage btile 0 into buffer 0 (slots now free) ----
    XSTAGE(0, bhalf * 2048);
    __syncthreads();                     // drains X staging + syncs

    for (int it = 0; it < 32; ++it) {
        const int buf = it & 1;
        const int b0  = bhalf * 2048 + it * 64;
        if (it < 31) XSTAGE(buf ^ 1, b0 + 64);   // prefetch next btile

        // deferred out-write for btile it-1 (reads ssbuf[buf^1]; the only
        // writer of that parity is finish(it+1), which is after our barrier)
        if (it > 0 && lane < 16) {
            const int bl = wv * 16 + lane;
            const float ssq = ssbuf[buf ^ 1][0][bl] + ssbuf[buf ^ 1][1][bl] +
                              ssbuf[buf ^ 1][2][bl] + ssbuf[buf ^ 1][3][bl];
            out[(size_t)(b0 - 64 + bl) * On + o] =
                1.0f / (1.0f + exp2f(bv * log2f(ssq)));
        }

        v16f acc[2][2];
#pragma unroll
        for (int mt = 0; mt < 2; ++mt)
#pragma unroll
            for (int nt = 0; nt < 2; ++nt)
#pragma unroll
                for (int rg = 0; rg < 16; ++rg) acc[mt][nt][rg] = 0.f;

#pragma unroll
        for (int ks = 0; ks < 16; ++ks) {
            v8bf xf[2];
#pragma unroll
            for (int nt = 0; nt < 2; ++nt)
                xf[nt] = *(const v8bf*)&Xs[buf][(ks * 2 + hw) * 64 + nt * 32 + l31][0];
#pragma unroll
            for (int mt = 0; mt < 2; ++mt)
#pragma unroll
                for (int nt = 0; nt < 2; ++nt)
                    acc[mt][nt] = __builtin_amdgcn_mfma_f32_32x32x16_bf16(
                        af[mt][ks], xf[nt], acc[mt][nt], 0, 0, 0);
        }

        // finish: partial sum_i y^2. C/D map (measured, m74/m101):
        // b = nt*32 + (lane&31), i_loc = (rg&3) + 8*(rg>>2) + 4*hw.
#pragma unroll
        for (int nt = 0; nt < 2; ++nt) {
            float v = 0.f;
#pragma unroll
            for (int mt = 0; mt < 2; ++mt)
#pragma unroll
                for (int rg = 0; rg < 16; ++rg) {
                    const float y = acc[mt][nt][rg] +
                        centL[wv * 64 + mt * 32 + (rg & 3) + 8 * (rg >> 2) + 4 * hw];
                    v += y * y;
                }
            v += __shfl_xor(v, 32);
            if (lane < 32) ssbuf[buf][wv][nt * 32 + lane] = v;
        }
        __syncthreads();   // Xs[buf^1] staged (covered by MFMA burst),
                           // ssbuf[buf] visible; next iter writes ssbuf[buf^1]
    }
    // tail: out-write for btile 31 (parity 1)
    if (lane < 16) {
        const int bl = wv * 16 + lane;
        const float ssq = ssbuf[1][0][bl] + ssbuf[1][1][bl] +
                          ssbuf[1][2][bl] + ssbuf[1][3][bl];
        out[(size_t)(bhalf * 2048 + 31 * 64 + bl) * On + o] =
            1.0f / (1.0f + exp2f(bv * log2f(ssq)));
    }
}

// ---------------------------------------------------------------------------
// Fallback (only if d_ws is too small): exact fp32, slow but correct.
// ---------------------------------------------------------------------------
__global__ void fallback_kernel(const float* __restrict__ x, const float* __restrict__ scales,
                                const float* __restrict__ rots, const float* __restrict__ cent,
                                const float* __restrict__ bvals, float* __restrict__ out) {
    const int b = blockIdx.x * blockDim.x + threadIdx.x;
    const int o = blockIdx.y;
    if (b >= Bn) return;
    const float* R  = rots + (size_t)o * Dn * Dn;
    const float* xv = x + (size_t)b * Dn;
    float ss = 0.f;
    for (int i = 0; i < Dn; ++i) {
        float a = cent[o * Dn + i];
        for (int j = 0; j < Dn; ++j) {
            const float w = (j > i) ? R[i * Dn + j]
                          : ((j < i) ? R[j * Dn + i] : scales[o * Dn + i]);
            a += w * xv[j];
        }
        ss += a * a;
    }
    out[(size_t)b * On + o] = 1.f / (1.f + powf(ss, bvals[o]));
}

extern "C" void kernel_launch(void* const* d_in, const int* in_sizes, int n_in,
                              void* d_out, int out_size, void* d_ws, size_t ws_size,
                              hipStream_t stream) {
    const float* x         = (const float*)d_in[0];
    const float* scales    = (const float*)d_in[1];
    const float* rots      = (const float*)d_in[2];
    const float* centroids = (const float*)d_in[3];
    const float* bvals     = (const float*)d_in[4];
    float* out = (float*)d_out;

    const size_t needX = (size_t)Bn * Dn * sizeof(unsigned short);      // 2.1 MB

    if (ws_size >= needX) {
        unsigned short* xbT = (unsigned short*)d_ws;
        prep_x<<<dim3(256), 256, 0, stream>>>(x, xbT);
        fuzzy_main<<<dim3(512), 256, 0, stream>>>(rots, scales, xbT, centroids, bvals, out);
    } else {
        fallback_kernel<<<dim3(Bn / 256, On), 256, 0, stream>>>(x, scales, rots, centroids,
                                                                bvals, out);
    }
}

// Round 5
// 224.453 us; speedup vs baseline: 1.0127x; 1.0064x over previous
//
#include <hip/hip_runtime.h>
#include <cstdint>
#include <cmath>

#define Bn 4096
#define Dn 256
#define On 256

typedef __bf16 v8bf __attribute__((ext_vector_type(8)));
typedef float  v16f __attribute__((ext_vector_type(16)));
typedef unsigned short us8 __attribute__((ext_vector_type(8)));

__device__ __forceinline__ unsigned short f2bf(float f) {
    // round-to-nearest-even fp32 -> bf16 (inputs are finite normals)
    unsigned int u = __builtin_bit_cast(unsigned int, f);
    unsigned int r = (u + 0x7fffu + ((u >> 16) & 1u)) >> 16;
    return (unsigned short)r;
}

__device__ __forceinline__ void gl_lds16(const void* g, void* l) {
    __builtin_amdgcn_global_load_lds(
        (const __attribute__((address_space(1))) void*)(uintptr_t)g,
        (__attribute__((address_space(3))) void*)(uintptr_t)l, 16, 0, 0);
}

// ---------------------------------------------------------------------------
// Kernel 1: x (fp32, [b][k] row-major) -> xbT (bf16, k-major 16B units:
// unit g = kc*Bn + b holds x[b][kc*8 .. kc*8+8]).  LDS-transpose per block.
// ---------------------------------------------------------------------------
__global__ __launch_bounds__(256) void prep_x(const float* __restrict__ x,
                                              unsigned short* __restrict__ xbT) {
    __shared__ float t[64][68];          // +4 pad: conflict-free col reads
    const int tid = threadIdx.x;
    const int bb = blockIdx.x >> 2;      // 64 b-tiles of 64
    const int kb = blockIdx.x & 3;       // 4 k-quarters of 64
    const int b0 = bb * 64;
#pragma unroll
    for (int s = 0; s < 4; ++s) {
        const int idx = s * 256 + tid;
        const int r = idx >> 4, c4 = idx & 15;
        const float4 v = *(const float4*)(x + (size_t)(b0 + r) * Dn + kb * 64 + c4 * 4);
        *(float4*)&t[r][c4 * 4] = v;
    }
    __syncthreads();
    const int lane = tid & 63, wv = tid >> 6;
#pragma unroll
    for (int s = 0; s < 2; ++s) {
        const int kcl = s * 4 + wv;      // 0..7 local k-chunk
        us8 u;
#pragma unroll
        for (int q = 0; q < 8; ++q) u[q] = f2bf(t[lane][kcl * 8 + q]);
        *(us8*)(xbT + ((size_t)(kb * 8 + kcl) * Bn + b0 + lane) * 8) = u;
    }
}

// ---------------------------------------------------------------------------
// Fragment extraction for one staged 64x64 tile pair (ti,tj), ti<=tj.
// Tile slot T is [64][64] fp32 with ROW-SWIZZLE: element (r,c) lives at
// T[r*64 + (c ^ ((r&7)<<2))] (pre-swizzled at the global source).
// af[mt][ks][j] = A[o][i = wv*64 + mt*32 + (lane&31)][k = ks*16 + (lane>>5)*8 + j]
// (32x32x16 A-operand layout; verified correct in round 4).
// ---------------------------------------------------------------------------
template <int TI, int TJ>
__device__ __forceinline__ void extract_pair(const float* T, v8bf (&af)[2][16],
                                             const float (&sc2)[2],
                                             int wv, int lane) {
    const int l31 = lane & 31, hw = lane >> 5;
    if (TI == TJ) {
        if (wv == TI) {                  // diagonal tile
#pragma unroll
            for (int mt = 0; mt < 2; ++mt) {
                const int r = mt * 32 + l31;
                const int mr = (r & 7) << 2;
#pragma unroll
                for (int kq = 0; kq < 4; ++kq) {
                    us8 u;
#pragma unroll
                    for (int q = 0; q < 8; ++q) {
                        const int c = kq * 16 + hw * 8 + q;
                        const float v = (r < c) ? T[r * 64 + (c ^ mr)]
                                      : ((r > c) ? T[c * 64 + (r ^ ((c & 7) << 2))]
                                                 : sc2[mt]);
                        u[q] = f2bf(v);
                    }
                    af[mt][TJ * 4 + kq] = __builtin_bit_cast(v8bf, u);
                }
            }
        }
    } else {
        if (wv == TI) {                  // row side: i-block=TI, k-block=TJ
#pragma unroll
            for (int mt = 0; mt < 2; ++mt) {
                const int r = mt * 32 + l31;
                const int mr = (r & 7) << 2;
#pragma unroll
                for (int kq = 0; kq < 4; ++kq) {
                    const int c0 = kq * 16 + hw * 8;
                    const float4 a = *(const float4*)&T[r * 64 + (c0 ^ mr)];
                    const float4 b = *(const float4*)&T[r * 64 + ((c0 + 4) ^ mr)];
                    us8 u;
                    u[0] = f2bf(a.x); u[1] = f2bf(a.y); u[2] = f2bf(a.z); u[3] = f2bf(a.w);
                    u[4] = f2bf(b.x); u[5] = f2bf(b.y); u[6] = f2bf(b.z); u[7] = f2bf(b.w);
                    af[mt][TJ * 4 + kq] = __builtin_bit_cast(v8bf, u);
                }
            }
        } else if (wv == TJ) {           // col side: i-block=TJ, k-block=TI
#pragma unroll
            for (int mt = 0; mt < 2; ++mt) {
                const int cL = mt * 32 + l31;
#pragma unroll
                for (int kq = 0; kq < 4; ++kq) {
                    us8 u;
#pragma unroll
                    for (int q = 0; q < 8; ++q) {
                        const int rL = kq * 16 + hw * 8 + q;
                        u[q] = f2bf(T[rL * 64 + (cL ^ ((rL & 7) << 2))]);
                    }
                    af[mt][TI * 4 + kq] = __builtin_bit_cast(v8bf, u);
                }
            }
        }
    }
}

// Inline-asm waits + compile-scheduler fence (rule #18).
#define WAITV(N)                                              \
    do {                                                      \
        asm volatile("s_waitcnt vmcnt(" #N ")" ::: "memory"); \
        __builtin_amdgcn_sched_barrier(0);                    \
    } while (0)
#define LGKM0()                                               \
    do {                                                      \
        asm volatile("s_waitcnt lgkmcnt(0)" ::: "memory");    \
        __builtin_amdgcn_sched_barrier(0);                    \
    } while (0)
#define BARF()                                                \
    do {                                                      \
        __builtin_amdgcn_sched_barrier(0);                    \
        __builtin_amdgcn_s_barrier();                         \
        __builtin_amdgcn_sched_barrier(0);                    \
    } while (0)

// Stage rot tile (TIv,TJv) into slot DST (16 KB) with source pre-swizzle.
#define STAGE_T(TIv, TJv, DST)                                               \
    do {                                                                     \
        const float* s_ = rbase + (TIv) * (64 * Dn) + (TJv) * 64;            \
        _Pragma("unroll")                                                    \
        for (int s = 0; s < 4; ++s) {                                        \
            const int idx = s * 256 + tid;                                   \
            const int r = idx >> 4, c4 = idx & 15;                           \
            gl_lds16(s_ + (size_t)r * Dn + ((c4 ^ (r & 7)) * 4),             \
                     (DST) + idx * 4);                                       \
        }                                                                    \
    } while (0)

// ---------------------------------------------------------------------------
// Kernel 2: fused A-build + GEMM + norm + bell, 32x32x16 MFMA, software-
// pipelined epilogue.  Per iteration: nt0 MFMA burst carries the distributed
// epilogue of the PREVIOUS iteration's nt1 accumulator; nt1 burst carries
// this iteration's nt0 epilogue.  ssbuf is parity-3 (iter j's halves land in
// iters j and j+1; read at j+2; the 3 parities touched per iter are distinct
// mod 3 -> race-free with the single per-iter barrier).  X staging uses 8
// persistent pointers (+1024B/iter) instead of full per-iter address calc.
// ---------------------------------------------------------------------------
__global__ __launch_bounds__(256, 2) void fuzzy_main(
    const float* __restrict__ rots, const float* __restrict__ scales,
    const unsigned short* __restrict__ xbT, const float* __restrict__ cent,
    const float* __restrict__ bvals, float* __restrict__ out) {
    __shared__ __align__(16) unsigned short Xs[2][2048][8];  // 64 KB dbuf
    __shared__ float ssbuf[3][4][64];                        // parity-3
    __shared__ float centL[Dn];

    const int tid  = threadIdx.x;
    const int lane = tid & 63;
    const int wv   = tid >> 6;
    const int l31  = lane & 31, hw = lane >> 5;
    // grid 512 = 8 xcd x 32 olow x 2 bhalf
    const int Lb = blockIdx.x;
    const int o     = (Lb & 7) * 32 + ((Lb >> 3) & 31);
    const int bhalf = Lb >> 8;
    const int bh0   = bhalf * 2048;

    centL[tid] = cent[o * Dn + tid];
    float sc2[2];
#pragma unroll
    for (int mt = 0; mt < 2; ++mt)
        sc2[mt] = scales[o * Dn + wv * 64 + mt * 32 + l31];
    const float bv = bvals[o];

    WAITV(0);   // drain the cent/scales vector loads -> clean vmcnt counting

    // ---- A-build prologue: 4 slots, 2 rounds in flight (proven r4) ----
    float* const S0 = (float*)&Xs[1][0][0];
    float* const S1 = S0 + 4096;
    float* const S2 = (float*)&Xs[0][0][0];
    float* const S3 = S2 + 4096;
    const float* const rbase = rots + ((size_t)o << 16);

    v8bf af[2][16];                      // 128 VGPRs

    STAGE_T(0, 1, S0); STAGE_T(2, 3, S1);        // R1
    STAGE_T(0, 2, S2); STAGE_T(1, 3, S3);        // R2   [16 in flight]
    WAITV(8); BARF();                            // R1 ready
    extract_pair<0, 1>(S0, af, sc2, wv, lane);
    extract_pair<2, 3>(S1, af, sc2, wv, lane);
    LGKM0(); BARF();
    STAGE_T(0, 3, S0); STAGE_T(1, 2, S1);        // R3
    WAITV(8); BARF();                            // R2 ready
    extract_pair<0, 2>(S2, af, sc2, wv, lane);
    extract_pair<1, 3>(S3, af, sc2, wv, lane);
    LGKM0(); BARF();
    STAGE_T(0, 0, S2); STAGE_T(1, 1, S3);        // R4
    WAITV(8); BARF();                            // R3 ready
    extract_pair<0, 3>(S0, af, sc2, wv, lane);
    extract_pair<1, 2>(S1, af, sc2, wv, lane);
    LGKM0(); BARF();
    STAGE_T(2, 2, S0); STAGE_T(3, 3, S1);        // R5
    WAITV(8); BARF();                            // R4 ready
    extract_pair<0, 0>(S2, af, sc2, wv, lane);
    extract_pair<1, 1>(S3, af, sc2, wv, lane);
    LGKM0(); BARF();
    WAITV(0); BARF();                            // R5 ready
    extract_pair<2, 2>(S0, af, sc2, wv, lane);
    extract_pair<3, 3>(S1, af, sc2, wv, lane);
    LGKM0(); BARF();

    // ---- X staging pointers (persistent, +1024B per btile) ----
    const unsigned short* px[8];
#pragma unroll
    for (int s = 0; s < 8; ++s)
        px[s] = xbT + ((size_t)(s * 4 + wv) * Bn + bh0 + lane) * 8;

    // stage btile 0 into buffer 0
#pragma unroll
    for (int s = 0; s < 8; ++s)
        gl_lds16(px[s], &Xs[0][s * 256 + tid][0]);
    __syncthreads();                     // drains X staging + syncs

    v16f acc1[2];                        // persistent nt1 accumulator
#pragma unroll
    for (int mt = 0; mt < 2; ++mt)
#pragma unroll
        for (int rg = 0; rg < 16; ++rg) acc1[mt][rg] = 0.f;

    for (int it = 0; it < 32; ++it) {
        const int buf  = it & 1;
        const int parc = it % 3;         // this iter's nt0 half
        const int parp = (it + 2) % 3;   // prev iter's nt1 half (= (it-1)%3)

        if (it < 31) {                   // prefetch next btile
#pragma unroll
            for (int s = 0; s < 8; ++s) {
                px[s] += 512;            // +64 b rows (shorts)
                gl_lds16(px[s], &Xs[buf ^ 1][s * 256 + tid][0]);
            }
        }

        // deferred out-write for btile it-2 (parity (it+1)%3)
        if (it >= 2 && lane < 16) {
            const int paro = (it + 1) % 3;
            const int bl = wv * 16 + lane;
            const float ssq = ssbuf[paro][0][bl] + ssbuf[paro][1][bl] +
                              ssbuf[paro][2][bl] + ssbuf[paro][3][bl];
            out[(size_t)(bh0 + (it - 2) * 64 + bl) * On + o] =
                1.0f / (1.0f + exp2f(bv * log2f(ssq)));
        }

        // ---- nt0 MFMA burst, carrying prev-iter nt1 epilogue chunks ----
        v16f acc0[2];
#pragma unroll
        for (int mt = 0; mt < 2; ++mt)
#pragma unroll
            for (int rg = 0; rg < 16; ++rg) acc0[mt][rg] = 0.f;

        float p0 = 0.f, p1 = 0.f;
        float4 c4p;
#pragma unroll
        for (int ks = 0; ks < 16; ++ks) {
            const v8bf xf0 = *(const v8bf*)&Xs[buf][(ks * 2 + hw) * 64 + l31][0];
            acc0[0] = __builtin_amdgcn_mfma_f32_32x32x16_bf16(af[0][ks], xf0, acc0[0], 0, 0, 0);
            acc0[1] = __builtin_amdgcn_mfma_f32_32x32x16_bf16(af[1][ks], xf0, acc0[1], 0, 0, 0);
            // epilogue chunk: elements e = 2ks, 2ks+1 of acc1 (prev iter)
            const int mt = ks >> 3, rg0 = (2 * ks) & 15;
            if ((ks & 1) == 0)
                c4p = *(const float4*)&centL[wv * 64 + mt * 32 + 8 * (rg0 >> 2) + 4 * hw];
            const float y0 = acc1[mt][rg0]     + ((ks & 1) ? c4p.z : c4p.x);
            const float y1 = acc1[mt][rg0 + 1] + ((ks & 1) ? c4p.w : c4p.y);
            p0 = fmaf(y0, y0, p0);
            p1 = fmaf(y1, y1, p1);
        }
        {   // finish prev nt1 epilogue (cols 32-63 of btile it-1)
            float v1 = p0 + p1;
            v1 += __shfl_xor(v1, 32);
            if (lane < 32) ssbuf[parp][wv][32 + lane] = v1;
        }

        // ---- nt1 MFMA burst, carrying this-iter nt0 epilogue chunks ----
#pragma unroll
        for (int mt = 0; mt < 2; ++mt)
#pragma unroll
            for (int rg = 0; rg < 16; ++rg) acc1[mt][rg] = 0.f;

        float q0 = 0.f, q1 = 0.f;
        float4 c4c;
#pragma unroll
        for (int ks = 0; ks < 16; ++ks) {
            const v8bf xf1 = *(const v8bf*)&Xs[buf][(ks * 2 + hw) * 64 + 32 + l31][0];
            acc1[0] = __builtin_amdgcn_mfma_f32_32x32x16_bf16(af[0][ks], xf1, acc1[0], 0, 0, 0);
            acc1[1] = __builtin_amdgcn_mfma_f32_32x32x16_bf16(af[1][ks], xf1, acc1[1], 0, 0, 0);
            const int mt = ks >> 3, rg0 = (2 * ks) & 15;
            if ((ks & 1) == 0)
                c4c = *(const float4*)&centL[wv * 64 + mt * 32 + 8 * (rg0 >> 2) + 4 * hw];
            const float y0 = acc0[mt][rg0]     + ((ks & 1) ? c4c.z : c4c.x);
            const float y1 = acc0[mt][rg0 + 1] + ((ks & 1) ? c4c.w : c4c.y);
            q0 = fmaf(y0, y0, q0);
            q1 = fmaf(y1, y1, q1);
        }
        {   // finish this-iter nt0 epilogue (cols 0-31 of btile it)
            float v0 = q0 + q1;
            v0 += __shfl_xor(v0, 32);
            if (lane < 32) ssbuf[parc][wv][lane] = v0;
        }

        __syncthreads();   // Xs[buf^1] staged (covered by MFMA bursts),
                           // ssbuf writes visible
    }

    // ---- tail: nt1 epilogue of btile 31, then last two out-writes ----
    {
        float p0 = 0.f, p1 = 0.f;
#pragma unroll
        for (int mt = 0; mt < 2; ++mt)
#pragma unroll
            for (int g = 0; g < 4; ++g) {
                const float4 c4 = *(const float4*)&centL[wv * 64 + mt * 32 + 8 * g + 4 * hw];
#pragma unroll
                for (int pq = 0; pq < 4; ++pq) {
                    const float y = acc1[mt][g * 4 + pq] +
                        ((pq == 0) ? c4.x : (pq == 1) ? c4.y : (pq == 2) ? c4.z : c4.w);
                    if (pq & 1) p1 = fmaf(y, y, p1); else p0 = fmaf(y, y, p0);
                }
            }
        float v1 = p0 + p1;
        v1 += __shfl_xor(v1, 32);
        if (lane < 32) ssbuf[31 % 3][wv][32 + lane] = v1;
    }
    __syncthreads();
    if (lane < 16) {
        const int bl = wv * 16 + lane;
#pragma unroll
        for (int j = 30; j <= 31; ++j) {
            const int par = j % 3;
            const float ssq = ssbuf[par][0][bl] + ssbuf[par][1][bl] +
                              ssbuf[par][2][bl] + ssbuf[par][3][bl];
            out[(size_t)(bh0 + j * 64 + bl) * On + o] =
                1.0f / (1.0f + exp2f(bv * log2f(ssq)));
        }
    }
}

// ---------------------------------------------------------------------------
// Fallback (only if d_ws is too small): exact fp32, slow but correct.
// ---------------------------------------------------------------------------
__global__ void fallback_kernel(const float* __restrict__ x, const float* __restrict__ scales,
                                const float* __restrict__ rots, const float* __restrict__ cent,
                                const float* __restrict__ bvals, float* __restrict__ out) {
    const int b = blockIdx.x * blockDim.x + threadIdx.x;
    const int o = blockIdx.y;
    if (b >= Bn) return;
    const float* R  = rots + (size_t)o * Dn * Dn;
    const float* xv = x + (size_t)b * Dn;
    float ss = 0.f;
    for (int i = 0; i < Dn; ++i) {
        float a = cent[o * Dn + i];
        for (int j = 0; j < Dn; ++j) {
            const float w = (j > i) ? R[i * Dn + j]
                          : ((j < i) ? R[j * Dn + i] : scales[o * Dn + i]);
            a += w * xv[j];
        }
        ss += a * a;
    }
    out[(size_t)b * On + o] = 1.f / (1.f + powf(ss, bvals[o]));
}

extern "C" void kernel_launch(void* const* d_in, const int* in_sizes, int n_in,
                              void* d_out, int out_size, void* d_ws, size_t ws_size,
                              hipStream_t stream) {
    const float* x         = (const float*)d_in[0];
    const float* scales    = (const float*)d_in[1];
    const float* rots      = (const float*)d_in[2];
    const float* centroids = (const float*)d_in[3];
    const float* bvals     = (const float*)d_in[4];
    float* out = (float*)d_out;

    const size_t needX = (size_t)Bn * Dn * sizeof(unsigned short);      // 2.1 MB

    if (ws_size >= needX) {
        unsigned short* xbT = (unsigned short*)d_ws;
        prep_x<<<dim3(256), 256, 0, stream>>>(x, xbT);
        fuzzy_main<<<dim3(512), 256, 0, stream>>>(rots, scales, xbT, centroids, bvals, out);
    } else {
        fallback_kernel<<<dim3(Bn / 256, On), 256, 0, stream>>>(x, scales, rots, centroids,
                                                                bvals, out);
    }
}